// Round 1
// 397.932 us; speedup vs baseline: 1.0069x; 1.0069x over previous
//
#include <hip/hip_runtime.h>
#include <hip/hip_bf16.h>

// Shapes: B=4, T=8, C=64, H=32, W=32, F=16, N=T*H*W=8192, HW=1024.
// pooled[b,n] = sum_c wbar[c]*x[b,t,c,h,w] + bbar   (conv1+avgpool collapsed)
// v[b,n]      = sigmoid(pooled[b,:] . ffnn1_w[n,:] + ffnn1_b[n])
// out[b,t,f,h,w] = v[b,n] * (sum_c g3_w[f,c]*x[b,t,c,h,w] + g3_b[f])
//
// R5: wave-per-2-rows gemv. Old structure had all 16 waves of a 1024-thread
// block redundantly butterfly-reducing 32 values over 64 lanes (3.1M ds ops
// kernel-wide) with 1 block/CU phase serialization. New: 256-thread blocks,
// 8 rows/block, 2 rows/wave, lanes split k; 48 shuffles/wave (16x fewer).
// W is streamed with nontemporal loads so pooled (128 KB) stays L2-resident.
// __launch_bounds__(256,4) -> VGPR<=128 -> 4 blocks/CU -> A/C phases of
// different blocks overlap.

#define HW 1024
#define Cc 64
#define Ff 16
#define Nn 8192

typedef __hip_bfloat16 bf16;
typedef float vf4 __attribute__((ext_vector_type(4)));
typedef unsigned int vu4 __attribute__((ext_vector_type(4)));

__device__ __forceinline__ float bf2f(bf16 h) { return __bfloat162float(h); }

template <bool F32>
__device__ __forceinline__ float ld1(const void* p, int i) {
    if constexpr (F32) return ((const float*)p)[i];
    else               return bf2f(((const bf16*)p)[i]);
}

// load 8 consecutive elements as floats (16B-aligned source)
template <bool F32>
__device__ __forceinline__ void ld8(const void* p, size_t i, float* dst) {
    if constexpr (F32) {
        const float* q = (const float*)p + i;
        float4 a = *reinterpret_cast<const float4*>(q);
        float4 b = *reinterpret_cast<const float4*>(q + 4);
        dst[0] = a.x; dst[1] = a.y; dst[2] = a.z; dst[3] = a.w;
        dst[4] = b.x; dst[5] = b.y; dst[6] = b.z; dst[7] = b.w;
    } else {
        const bf16* q = (const bf16*)p + i;
        uint4 u = *reinterpret_cast<const uint4*>(q);
        dst[0] = __uint_as_float(u.x << 16);
        dst[1] = __uint_as_float(u.x & 0xffff0000u);
        dst[2] = __uint_as_float(u.y << 16);
        dst[3] = __uint_as_float(u.y & 0xffff0000u);
        dst[4] = __uint_as_float(u.z << 16);
        dst[5] = __uint_as_float(u.z & 0xffff0000u);
        dst[6] = __uint_as_float(u.w << 16);
        dst[7] = __uint_as_float(u.w & 0xffff0000u);
    }
}

// nontemporal variant for the one-pass W stream (don't evict pooled from L2)
template <bool F32>
__device__ __forceinline__ void ld8nt(const void* p, size_t i, float* dst) {
    if constexpr (F32) {
        const vf4* q = (const vf4*)((const float*)p + i);
        vf4 a = __builtin_nontemporal_load(q);
        vf4 b = __builtin_nontemporal_load(q + 1);
        dst[0] = a[0]; dst[1] = a[1]; dst[2] = a[2]; dst[3] = a[3];
        dst[4] = b[0]; dst[5] = b[1]; dst[6] = b[2]; dst[7] = b[3];
    } else {
        const vu4* q = (const vu4*)((const bf16*)p + i);
        vu4 u = __builtin_nontemporal_load(q);
        dst[0] = __uint_as_float(u[0] << 16);
        dst[1] = __uint_as_float(u[0] & 0xffff0000u);
        dst[2] = __uint_as_float(u[1] << 16);
        dst[3] = __uint_as_float(u[1] & 0xffff0000u);
        dst[4] = __uint_as_float(u[2] << 16);
        dst[5] = __uint_as_float(u[2] & 0xffff0000u);
        dst[6] = __uint_as_float(u[3] << 16);
        dst[7] = __uint_as_float(u[3] & 0xffff0000u);
    }
}

// ---------------- Kernel 1: pooled (+ inline dtype detect) ----------------
// grid = 256 blocks x 128 threads. Each thread owns one (bt, hw) pair.
template <bool F32>
__device__ __forceinline__ void pool_body(const void* __restrict__ x,
                                          const void* __restrict__ conv1_w,
                                          const void* __restrict__ conv1_b,
                                          float* __restrict__ pooled) {
    __shared__ float wbar[Cc];
    __shared__ float bbar;
    int tid = threadIdx.x;  // 0..127
    if (tid < Cc) {
        float s = 0.f;
        #pragma unroll
        for (int f = 0; f < Ff; ++f) s += ld1<F32>(conv1_w, f * Cc + tid);
        wbar[tid] = s * (1.f / 16.f);
    }
    if (tid == 64) {
        float s = 0.f;
        #pragma unroll
        for (int f = 0; f < Ff; ++f) s += ld1<F32>(conv1_b, f);
        bbar = s * (1.f / 16.f);
    }
    __syncthreads();

    int bt = blockIdx.x >> 3;                  // 0..31 (b*8+t)
    int hw = ((blockIdx.x & 7) << 7) + tid;    // 0..1023
    size_t base = (size_t)bt * Cc * HW + hw;
    float acc = 0.f;
    #pragma unroll
    for (int c = 0; c < Cc; ++c) acc += wbar[c] * ld1<F32>(x, base + c * HW);

    int b = bt >> 3, t = bt & 7;
    pooled[b * Nn + t * HW + hw] = acc + bbar;
}

__global__ void pool_kernel(const void* __restrict__ x,
                            const void* __restrict__ conv1_w,
                            const void* __restrict__ conv1_b,
                            float* __restrict__ pooled,
                            int* __restrict__ flag) {
    // dtype detect: even uint16 halfwords of a bf16 N(0,1) array have
    // exponent in [0x6F,0x83] ~always; for f32 arrays they are low mantissa
    // bits (~uniform, ~8% pass). 256 samples, threshold 128.
    __shared__ int sflag;
    __shared__ int wcnt[2];
    int tid = threadIdx.x;  // 0..127
    const unsigned short* xs = (const unsigned short*)x;
    unsigned short u0 = xs[4 * tid], u1 = xs[4 * tid + 2];
    int e0 = (u0 >> 7) & 0xFF, e1 = (u1 >> 7) & 0xFF;
    int c = ((e0 >= 0x6F && e0 <= 0x83) ? 1 : 0)
          + ((e1 >= 0x6F && e1 <= 0x83) ? 1 : 0);
    #pragma unroll
    for (int off = 32; off > 0; off >>= 1) c += __shfl_down(c, off);
    if ((tid & 63) == 0) wcnt[tid >> 6] = c;
    __syncthreads();
    if (tid == 0) {
        int f = (wcnt[0] + wcnt[1] < 128) ? 1 : 0;  // 1 => float32 inputs
        sflag = f;
        flag[0] = f;  // all blocks write the same value (benign race)
    }
    __syncthreads();
    if (sflag) pool_body<true>(x, conv1_w, conv1_b, pooled);
    else       pool_body<false>(x, conv1_w, conv1_b, pooled);
}

// ---------------- Kernel 2 (fused): v = sigmoid(pooled@W^T+b); out ----------
// grid = 1024 blocks x 256 threads; 8 rows per block (one t, 8 consecutive
// hw); 4 waves/block, 2 rows per wave, lanes split k (8-elem chunks).
template <bool F32>
__device__ __forceinline__ void gemv_out_body(const void* __restrict__ w,
                                              const void* __restrict__ bias,
                                              const float* __restrict__ pooled,
                                              const void* __restrict__ x,
                                              const void* __restrict__ g3_w,
                                              const void* __restrict__ g3_b,
                                              void* __restrict__ out) {
    int tid  = threadIdx.x;          // 0..255
    int wave = tid >> 6, lane = tid & 63;
    int n0   = blockIdx.x * 8;
    int t    = blockIdx.x >> 7;      // n0 / 1024
    int hw0  = (blockIdx.x & 127) * 8;

    // pad rows to 68 floats: xsh banks (i*4+c)%32 distinct over i (b128-safe),
    // g3s banks (f*4+c)%32 2-way over 16 f (free), 16B alignment kept.
    __shared__ __align__(16) float xsh[4][8][68];  // [b][i][c]  ~8.7 KB
    __shared__ __align__(16) float g3s[Ff][68];    //            ~4.3 KB
    __shared__ float vsh[4][8];
    __shared__ float bsh[Ff];

    // ---- staging for the out-stage (x slice transposed, g3) ----
    {
        int b = tid >> 6, c = tid & 63;
        float tmp[8];
        ld8<F32>(x, ((size_t)(b * 8 + t) * Cc + c) * HW + hw0, tmp);
        #pragma unroll
        for (int i = 0; i < 8; ++i) xsh[b][i][c] = tmp[i];  // 2-way bank: free
    }
    #pragma unroll
    for (int rep = 0; rep < 4; ++rep) {
        int idx = rep * 256 + tid;    // 1024 g3 weights
        g3s[idx >> 6][idx & 63] = ld1<F32>(g3_w, idx);
    }
    if (tid < Ff) bsh[tid] = ld1<F32>(g3_b, tid);

    // ---- gemv: wave handles rows r0, r0+1; lane handles k = it*512+lane*8 ----
    int r0 = n0 + wave * 2;
    float acc[2][4];
    #pragma unroll
    for (int r = 0; r < 2; ++r)
        #pragma unroll
        for (int b = 0; b < 4; ++b) acc[r][b] = 0.f;

    #pragma unroll 2
    for (int it = 0; it < 16; ++it) {
        int k = it * 512 + lane * 8;
        float wv0[8], wv1[8];
        ld8nt<F32>(w, (size_t)r0 * Nn + k, wv0);
        ld8nt<F32>(w, (size_t)(r0 + 1) * Nn + k, wv1);
        #pragma unroll
        for (int b = 0; b < 4; ++b) {
            const float* pp = pooled + b * Nn + k;   // L2-resident (128 KB)
            vf4 p0 = *(const vf4*)pp;
            vf4 p1 = *(const vf4*)(pp + 4);
            float pv[8] = {p0[0], p0[1], p0[2], p0[3],
                           p1[0], p1[1], p1[2], p1[3]};
            #pragma unroll
            for (int j = 0; j < 8; ++j) {
                acc[0][b] = fmaf(wv0[j], pv[j], acc[0][b]);
                acc[1][b] = fmaf(wv1[j], pv[j], acc[1][b]);
            }
        }
    }

    // butterfly: 8 values x 6 steps = 48 shuffles/wave (was 192/wave x 16)
    #pragma unroll
    for (int r = 0; r < 2; ++r)
        #pragma unroll
        for (int b = 0; b < 4; ++b) {
            float s = acc[r][b];
            #pragma unroll
            for (int off = 1; off < 64; off <<= 1) s += __shfl_xor(s, off);
            acc[r][b] = s;
        }

    if (lane == 0) {
        #pragma unroll
        for (int r = 0; r < 2; ++r) {
            float bb = ld1<F32>(bias, r0 + r);
            #pragma unroll
            for (int b = 0; b < 4; ++b)
                vsh[b][wave * 2 + r] = 1.f / (1.f + __expf(-(acc[r][b] + bb)));
        }
    }
    __syncthreads();

    // ---- out-stage: 512 outputs (b,f,i), 2 per thread ----
    {
        int b = tid >> 6, f = (tid >> 2) & 15, i0 = (tid & 3) * 2;
        float a0 = bsh[f], a1 = a0;
        #pragma unroll
        for (int c4 = 0; c4 < Cc; c4 += 4) {
            vf4 gv = *(const vf4*)&g3s[f][c4];
            vf4 x0 = *(const vf4*)&xsh[b][i0][c4];
            vf4 x1 = *(const vf4*)&xsh[b][i0 + 1][c4];
            #pragma unroll
            for (int j = 0; j < 4; ++j) {
                a0 = fmaf(gv[j], x0[j], a0);
                a1 = fmaf(gv[j], x1[j], a1);
            }
        }
        float v0 = vsh[b][i0] * a0;
        float v1 = vsh[b][i0 + 1] * a1;
        size_t oi = ((size_t)(b * 8 + t) * Ff + f) * HW + hw0 + i0;
        if constexpr (F32) {
            *reinterpret_cast<float2*>((float*)out + oi) = make_float2(v0, v1);
        } else {
            __hip_bfloat162 hh = __halves2bfloat162(__float2bfloat16(v0),
                                                    __float2bfloat16(v1));
            *reinterpret_cast<__hip_bfloat162*>((bf16*)out + oi) = hh;
        }
    }
}

__global__ __launch_bounds__(256, 4)
void gemv_out_kernel(const void* __restrict__ w,
                     const void* __restrict__ bias,
                     const float* __restrict__ pooled,
                     const void* __restrict__ x,
                     const void* __restrict__ g3_w,
                     const void* __restrict__ g3_b,
                     void* __restrict__ out,
                     const int* __restrict__ flag) {
    if (flag[0]) gemv_out_body<true>(w, bias, pooled, x, g3_w, g3_b, out);
    else         gemv_out_body<false>(w, bias, pooled, x, g3_w, g3_b, out);
}

extern "C" void kernel_launch(void* const* d_in, const int* in_sizes, int n_in,
                              void* d_out, int out_size, void* d_ws, size_t ws_size,
                              hipStream_t stream) {
    const void* x       = d_in[0];
    // d_in[1] = x1 (unused by the reference forward)
    const void* conv1_w = d_in[2];
    const void* conv1_b = d_in[3];
    const void* g3_w    = d_in[4];
    const void* g3_b    = d_in[5];
    const void* ffnn1_w = d_in[6];
    const void* ffnn1_b = d_in[7];

    int*   flag   = (int*)d_ws;                    // 64 B slot
    float* pooled = (float*)d_ws + 16;             // 4*8192 floats = 128 KB

    pool_kernel<<<256, 128, 0, stream>>>(x, conv1_w, conv1_b, pooled, flag);
    gemv_out_kernel<<<1024, 256, 0, stream>>>(ffnn1_w, ffnn1_b, pooled,
                                              x, g3_w, g3_b, d_out, flag);
}